// Round 3
// baseline (170.069 us; speedup 1.0000x reference)
//
#include <hip/hip_runtime.h>
#include <math.h>

// spaceGraph via f16 MFMA, round 4b (R2 fix: __builtin_amdgcn_cvt_pkrtz
// returns an __fp16 ext-vector, not _Float16 -- bridge via __fp16x2 temp).
// R4 vs R3 (latency-bound: MfmaUtil 8.5 / VALU 33 / HBM 22 / occ 17 -> nothing
// saturated; LDS 54272B capped us at 3 blocks/CU):
//  - rank-1 decomposition: S = X*(W1^T W2)*X^T + u 1^T + 1 v^T + c with
//    u = X W1^T b2, v = X W2^T b1, c = b1.b2. One projection T = X*G instead
//    of Q and K (MFMA 96 -> 80 per wave); u/v/c folded into the S-accumulator
//    INIT (no per-element softmax cost); K buffer deleted from LDS -- phase-3
//    B-frags are contiguous 32B X-row reads from global (L1/L2-hot).
//  - A written in two 64-col halves into the dead T buffer (wave-private):
//    LDS 54272 -> 36864 B -> 4 blocks/CU (16 waves/CU), __launch_bounds__(256,4).
//  - 1 barrier (was 2): post-barrier LDS traffic is wave-private (T, A) or
//    reads pre-barrier data (Xt, u, v).
//  - cvt_pkrtz packed f32->f16 on MFMA-feed converts; phase-2 b16 stores halved.

namespace {
constexpr int H = 8, NV = 128, HEAD = 64, B = 4, L = 8192;
constexpr int P = L / NV;        // 64
constexpr int D = H * HEAD;      // 512
constexpr int RS = P * D;        // 32768 floats between vars j -> j+1

constexpr int XT_S = 136;        // Xt row stride (halfs); 64 rows (dims)
constexpr int TA_S = 72;         // T / A_half row stride (halfs); 128 rows

typedef _Float16 half8  __attribute__((ext_vector_type(8)));
typedef _Float16 half2v __attribute__((ext_vector_type(2)));
typedef __fp16   fp16x2 __attribute__((ext_vector_type(2)));
typedef float    floatx4 __attribute__((ext_vector_type(4)));

__device__ __forceinline__ floatx4 mfma16(half8 a, half8 b, floatx4 c) {
    return __builtin_amdgcn_mfma_f32_16x16x32_f16(a, b, c, 0, 0, 0);
}

__device__ __forceinline__ half8 cvt8(float4 a, float4 b) {
    fp16x2 p0 = __builtin_amdgcn_cvt_pkrtz(a.x, a.y);
    fp16x2 p1 = __builtin_amdgcn_cvt_pkrtz(a.z, a.w);
    fp16x2 p2 = __builtin_amdgcn_cvt_pkrtz(b.x, b.y);
    fp16x2 p3 = __builtin_amdgcn_cvt_pkrtz(b.z, b.w);
    half8 r;
    r[0] = (_Float16)p0[0]; r[1] = (_Float16)p0[1];
    r[2] = (_Float16)p1[0]; r[3] = (_Float16)p1[1];
    r[4] = (_Float16)p2[0]; r[5] = (_Float16)p2[1];
    r[6] = (_Float16)p3[0]; r[7] = (_Float16)p3[1];
    return r;
}

// ---- pre-pass: Gth[e][d] = sum_n w1[n][d]*w2[n][e] (f16), plus
// g1f[d] = sum_n w1[n][d]*b2[n], g2f[d] = sum_n w2[n][d]*b1[n], cf = b1.b2 ----
__global__ __launch_bounds__(256) void pack_g(
    const float* __restrict__ w1, const float* __restrict__ w2,
    const float* __restrict__ b1, const float* __restrict__ b2,
    _Float16* __restrict__ gth, float* __restrict__ g1f,
    float* __restrict__ g2f, float* __restrict__ cf)
{
    const int t = threadIdx.x;
    if (blockIdx.x == 16) {
        if (t < 64) {
            float a = 0.f;
            #pragma unroll 8
            for (int n = 0; n < 64; ++n) a = fmaf(w1[n * 64 + t], b2[n], a);
            g1f[t] = a;
        } else if (t < 128) {
            const int d = t - 64;
            float a = 0.f;
            #pragma unroll 8
            for (int n = 0; n < 64; ++n) a = fmaf(w2[n * 64 + d], b1[n], a);
            g2f[d] = a;
        } else if (t == 128) {
            float a = 0.f;
            for (int n = 0; n < 64; ++n) a = fmaf(b1[n], b2[n], a);
            cf[0] = a;
        }
        return;
    }
    const int gid = blockIdx.x * 256 + t;
    const int d = gid & 63, e = gid >> 6;
    float a = 0.f;
    #pragma unroll 8
    for (int n = 0; n < 64; ++n) a = fmaf(w1[n * 64 + d], w2[n * 64 + e], a);
    gth[e * 64 + d] = (_Float16)a;
}

__global__ __launch_bounds__(256, 4) void space_graph_mfma4(
    const float* __restrict__ x, const _Float16* __restrict__ gth,
    const float* __restrict__ g1f, const float* __restrict__ g2f,
    const float* __restrict__ cf, float* __restrict__ out)
{
    // 64*136 + 128*72 = 17920 halfs = 35840 B, + 1024 B u/v -> 36864 B
    // -> 4 blocks/CU (147456 <= 160 KiB).
    __shared__ _Float16 lds[64 * XT_S + NV * TA_S];
    __shared__ float uv[2 * NV];
    _Float16* Xt = lds;                  // X^T: [dim][var], phases 1 -> 5
    _Float16* TA = lds + 64 * XT_S;      // T (phases 2-3), A_half (phases 4-5)
    float* u_lds = uv;                   // u[i] (row term)
    float* v_lds = uv + NV;              // v[j] (col term)

    const int t    = threadIdx.x;
    const int lane = t & 63;
    const int w    = t >> 6;             // wave -> owns S/O rows 32w..32w+31
    const int col  = lane & 15;
    const int quad = lane >> 4;

    const int blk = blockIdx.x;
    const int p = blk & (P - 1);
    const int h = (blk >> 6) & (H - 1);
    const int b = blk >> 9;
    const size_t base = ((size_t)b * L + (size_t)p) * D + (size_t)h * HEAD;

    // ---- Phase 1: build Xt (f16 transposed X) ----
    {
        const int c  = t & 15;           // float4 column
        const int tt = t >> 4;
        #pragma unroll
        for (int it = 0; it < 4; ++it) {
            const int j0 = 2 * (tt + 16 * it);
            const float4 v0 = *(const float4*)(x + base + (size_t)j0 * RS + c * 4);
            const float4 v1 = *(const float4*)(x + base + (size_t)(j0 + 1) * RS + c * 4);
            const float va[4] = {v0.x, v0.y, v0.z, v0.w};
            const float vb[4] = {v1.x, v1.y, v1.z, v1.w};
            #pragma unroll
            for (int q = 0; q < 4; ++q) {
                half2v pr; pr[0] = (_Float16)va[q]; pr[1] = (_Float16)vb[q];
                *(half2v*)&Xt[(4 * c + q) * XT_S + j0] = pr;
            }
        }
    }

    // ---- Phase 2: T = X*G (MFMA); u,v rank-1 terms (VALU, f32) ----
    floatx4 tacc[2][4];
    #pragma unroll
    for (int mt = 0; mt < 2; ++mt)
        #pragma unroll
        for (int nt = 0; nt < 4; ++nt) tacc[mt][nt] = (floatx4)0.0f;

    half8 axf[2][2];
    float up[2] = {0.f, 0.f}, vp[2] = {0.f, 0.f};
    #pragma unroll
    for (int ks = 0; ks < 2; ++ks) {
        const float4 ga = *(const float4*)(g1f + quad * 8 + 32 * ks);
        const float4 gb = *(const float4*)(g1f + quad * 8 + 32 * ks + 4);
        const float4 ha = *(const float4*)(g2f + quad * 8 + 32 * ks);
        const float4 hb = *(const float4*)(g2f + quad * 8 + 32 * ks + 4);
        #pragma unroll
        for (int mt = 0; mt < 2; ++mt) {
            const int row = 32 * w + 16 * mt + col;
            const float* src = x + base + (size_t)row * RS + quad * 8 + 32 * ks;
            const float4 v0 = *(const float4*)src;
            const float4 v1 = *(const float4*)(src + 4);
            axf[mt][ks] = cvt8(v0, v1);
            up[mt] += v0.x * ga.x + v0.y * ga.y + v0.z * ga.z + v0.w * ga.w
                    + v1.x * gb.x + v1.y * gb.y + v1.z * gb.z + v1.w * gb.w;
            vp[mt] += v0.x * ha.x + v0.y * ha.y + v0.z * ha.z + v0.w * ha.w
                    + v1.x * hb.x + v1.y * hb.y + v1.z * hb.z + v1.w * hb.w;
        }
    }

    #pragma unroll
    for (int ks = 0; ks < 2; ++ks)
        #pragma unroll
        for (int nt = 0; nt < 4; ++nt) {
            const half8 gb8 = *(const half8*)&gth[(col + 16 * nt) * HEAD + quad * 8 + 32 * ks];
            #pragma unroll
            for (int mt = 0; mt < 2; ++mt)
                tacc[mt][nt] = mfma16(axf[mt][ks], gb8, tacc[mt][nt]);
        }

    // u/v quad-reduce (dims are split across quads) + LDS store
    #pragma unroll
    for (int mt = 0; mt < 2; ++mt) {
        float uu = up[mt]; uu += __shfl_xor(uu, 16); uu += __shfl_xor(uu, 32);
        float vv = vp[mt]; vv += __shfl_xor(vv, 16); vv += __shfl_xor(vv, 32);
        if (quad == 0) u_lds[32 * w + 16 * mt + col] = uu;
        if (quad == 1) v_lds[32 * w + 16 * mt + col] = vv;
    }

    // T store (no bias -- biases live in u/v/c)
    #pragma unroll
    for (int mt = 0; mt < 2; ++mt)
        #pragma unroll
        for (int r = 0; r < 4; ++r) {
            const int R = 32 * w + 16 * mt + quad * 4 + r;
            _Float16* trow = &TA[R * TA_S + col];
            #pragma unroll
            for (int nt = 0; nt < 4; ++nt)
                trow[nt * 16] = (_Float16)(tacc[mt][nt][r]);
        }
    __syncthreads();   // the ONLY barrier: covers Xt (ph5) and v (ph3 init)

    // ---- Phase 3: S = T*X^T + (u_i + v_j + c) via accumulator init ----
    const float cc = cf[0];
    float ucr[2][4];
    #pragma unroll
    for (int mt = 0; mt < 2; ++mt)
        #pragma unroll
        for (int r = 0; r < 4; ++r)
            ucr[mt][r] = u_lds[32 * w + 16 * mt + quad * 4 + r] + cc;
    float vrow[8];
    #pragma unroll
    for (int nt = 0; nt < 8; ++nt) vrow[nt] = v_lds[col + 16 * nt];

    floatx4 sacc[2][8];
    #pragma unroll
    for (int mt = 0; mt < 2; ++mt)
        #pragma unroll
        for (int nt = 0; nt < 8; ++nt)
            #pragma unroll
            for (int r = 0; r < 4; ++r)
                sacc[mt][nt][r] = ucr[mt][r] + vrow[nt];

    #pragma unroll
    for (int ks = 0; ks < 2; ++ks) {
        half8 taf[2];
        #pragma unroll
        for (int mt = 0; mt < 2; ++mt)
            taf[mt] = *(const half8*)&TA[(32 * w + 16 * mt + col) * TA_S + quad * 8 + 32 * ks];
        #pragma unroll
        for (int nt = 0; nt < 8; ++nt) {
            // B-frag = contiguous 32B X-row read (L1/L2-hot), no K buffer
            const float* bs = x + base + (size_t)(col + 16 * nt) * RS + quad * 8 + 32 * ks;
            const half8 xb = cvt8(*(const float4*)bs, *(const float4*)(bs + 4));
            #pragma unroll
            for (int mt = 0; mt < 2; ++mt)
                sacc[mt][nt] = mfma16(taf[mt], xb, sacc[mt][nt]);
        }
    }

    // ---- Phase 4: A = softmax(gelu(S)); normalized weights back into sacc ----
    #pragma unroll
    for (int mt = 0; mt < 2; ++mt)
        #pragma unroll
        for (int r = 0; r < 4; ++r) {
            float wv[8]; float rs = 0.f;
            #pragma unroll
            for (int nt = 0; nt < 8; ++nt) {
                const float s  = sacc[mt][nt][r];
                const float u  = s * fmaf(s * s, 0.035677408137f, 0.7978845608f);
                const float em = __expf(-2.0f * u);
                const float g  = s * __builtin_amdgcn_rcpf(1.0f + em);
                const float e  = __expf(g);
                wv[nt] = e; rs += e;
            }
            rs += __shfl_xor(rs, 1); rs += __shfl_xor(rs, 2);
            rs += __shfl_xor(rs, 4); rs += __shfl_xor(rs, 8);
            const float inv = __builtin_amdgcn_rcpf(rs);
            #pragma unroll
            for (int nt = 0; nt < 8; ++nt) sacc[mt][nt][r] = wv[nt] * inv;
        }

    // ---- Phase 4a/5a: A_half <- vars 0..63 (wave-private rows), O += A*X ----
    #pragma unroll
    for (int mt = 0; mt < 2; ++mt)
        #pragma unroll
        for (int r = 0; r < 4; ++r) {
            const int R = 32 * w + 16 * mt + quad * 4 + r;
            _Float16* arow = &TA[R * TA_S + col];
            #pragma unroll
            for (int nt = 0; nt < 4; ++nt)
                arow[nt * 16] = (_Float16)(sacc[mt][nt][r]);
        }

    floatx4 oacc[2][4];
    #pragma unroll
    for (int mt = 0; mt < 2; ++mt)
        #pragma unroll
        for (int nt = 0; nt < 4; ++nt) oacc[mt][nt] = (floatx4)0.0f;

    #pragma unroll
    for (int kh = 0; kh < 2; ++kh) {
        half8 aaf[2];
        #pragma unroll
        for (int mt = 0; mt < 2; ++mt)
            aaf[mt] = *(const half8*)&TA[(32 * w + 16 * mt + col) * TA_S + quad * 8 + 32 * kh];
        #pragma unroll
        for (int nt = 0; nt < 4; ++nt) {
            const half8 xb = *(const half8*)&Xt[(col + 16 * nt) * XT_S + quad * 8 + 32 * kh];
            #pragma unroll
            for (int mt = 0; mt < 2; ++mt)
                oacc[mt][nt] = mfma16(aaf[mt], xb, oacc[mt][nt]);
        }
    }

    // ---- Phase 4b/5b: A_half <- vars 64..127, O += A*X ----
    #pragma unroll
    for (int mt = 0; mt < 2; ++mt)
        #pragma unroll
        for (int r = 0; r < 4; ++r) {
            const int R = 32 * w + 16 * mt + quad * 4 + r;
            _Float16* arow = &TA[R * TA_S + col];
            #pragma unroll
            for (int nt = 4; nt < 8; ++nt)
                arow[(nt - 4) * 16] = (_Float16)(sacc[mt][nt][r]);
        }

    #pragma unroll
    for (int kh = 0; kh < 2; ++kh) {
        half8 aaf[2];
        #pragma unroll
        for (int mt = 0; mt < 2; ++mt)
            aaf[mt] = *(const half8*)&TA[(32 * w + 16 * mt + col) * TA_S + quad * 8 + 32 * kh];
        #pragma unroll
        for (int nt = 0; nt < 4; ++nt) {
            const half8 xb = *(const half8*)&Xt[(col + 16 * nt) * XT_S + quad * 8 + 32 * (kh + 2)];
            #pragma unroll
            for (int mt = 0; mt < 2; ++mt)
                oacc[mt][nt] = mfma16(aaf[mt], xb, oacc[mt][nt]);
        }
    }

    // ---- Epilogue: direct stores (quad-wise 64B segments) ----
    #pragma unroll
    for (int mt = 0; mt < 2; ++mt)
        #pragma unroll
        for (int r = 0; r < 4; ++r) {
            const int i = 32 * w + 16 * mt + quad * 4 + r;
            float* orow = out + base + (size_t)i * RS + col;
            #pragma unroll
            for (int nt = 0; nt < 4; ++nt)
                orow[nt * 16] = oacc[mt][nt][r];
        }
}
} // namespace

extern "C" void kernel_launch(void* const* d_in, const int* in_sizes, int n_in,
                              void* d_out, int out_size, void* d_ws, size_t ws_size,
                              hipStream_t stream) {
    const float* x  = (const float*)d_in[0];
    const float* w1 = (const float*)d_in[1];
    const float* b1 = (const float*)d_in[2];
    const float* w2 = (const float*)d_in[3];
    const float* b2 = (const float*)d_in[4];
    float* out = (float*)d_out;

    _Float16* gth = (_Float16*)d_ws;                  // 8192 B: G^T f16 (64x64)
    float* g1f = (float*)((char*)d_ws + 8192);        // 256 B
    float* g2f = g1f + 64;                            // 256 B
    float* cf  = g2f + 64;                            // 4 B

    hipLaunchKernelGGL(pack_g, dim3(17), dim3(256), 0, stream,
                       w1, w2, b1, b2, gth, g1f, g2f, cf);
    hipLaunchKernelGGL(space_graph_mfma4, dim3(B * H * P), dim3(256), 0, stream,
                       x, gth, g1f, g2f, cf, out);
}

// Round 4
// 142.260 us; speedup vs baseline: 1.1955x; 1.1955x over previous
//
#include <hip/hip_runtime.h>
#include <math.h>

// spaceGraph via f16 MFMA, round 5.
// R5 vs R4 (post-mortem: R4's phase-3 global X re-reads were NOT cache-hot --
// FETCH +24MB, 128KB-stride rows thrash L1/L2 sets, latency-bound, 82us > R3's
// 57.7): keep the rank-1 decomposition, move phase-3 B-operand back on-chip.
//  - S = X*(W1^T W2)*X^T + u 1^T + 1 v^T + c (u = X W1^T b2, v = X W2^T b1,
//    c = b1.b2): one projection T = X*G (80 MFMA/wave vs R3's 96).
//  - NEW: Xh = row-major f16 X (128x72) written in phase 1 (converts shared
//    with Xt; +2 ds_write_b64/thread/iter). Phase 3 reads taf(T) + xb(Xh)
//    from LDS -- zero global traffic after phase 2.
//  - LDS = Xt(64x136) + Xh(128x72) + T/A(128x72) = 54272 B -> 3 blocks/CU
//    (exactly R3's footprint). v[128] (512B) lives in Xt row-padding halfs;
//    u stays in registers (consumed by the producing wave, via __shfl).
//  - Still 1 barrier: Xh/Xt/v written pre-barrier, T/A wave-private.

namespace {
constexpr int H = 8, NV = 128, HEAD = 64, B = 4, L = 8192;
constexpr int P = L / NV;        // 64
constexpr int D = H * HEAD;      // 512
constexpr int RS = P * D;        // 32768 floats between vars j -> j+1

constexpr int XT_S = 136;        // Xt row stride (halfs); 64 rows (dims)
constexpr int XH_S = 72;         // Xh row stride (halfs); 128 rows (vars)
constexpr int TA_S = 72;         // T / A_half row stride (halfs); 128 rows

typedef _Float16 half8  __attribute__((ext_vector_type(8)));
typedef _Float16 half4h __attribute__((ext_vector_type(4)));
typedef _Float16 half2v __attribute__((ext_vector_type(2)));
typedef __fp16   fp16x2 __attribute__((ext_vector_type(2)));
typedef float    floatx4 __attribute__((ext_vector_type(4)));

__device__ __forceinline__ floatx4 mfma16(half8 a, half8 b, floatx4 c) {
    return __builtin_amdgcn_mfma_f32_16x16x32_f16(a, b, c, 0, 0, 0);
}

__device__ __forceinline__ half8 cvt8(float4 a, float4 b) {
    fp16x2 p0 = __builtin_amdgcn_cvt_pkrtz(a.x, a.y);
    fp16x2 p1 = __builtin_amdgcn_cvt_pkrtz(a.z, a.w);
    fp16x2 p2 = __builtin_amdgcn_cvt_pkrtz(b.x, b.y);
    fp16x2 p3 = __builtin_amdgcn_cvt_pkrtz(b.z, b.w);
    half8 r;
    r[0] = (_Float16)p0[0]; r[1] = (_Float16)p0[1];
    r[2] = (_Float16)p1[0]; r[3] = (_Float16)p1[1];
    r[4] = (_Float16)p2[0]; r[5] = (_Float16)p2[1];
    r[6] = (_Float16)p3[0]; r[7] = (_Float16)p3[1];
    return r;
}

// v[128] stashed in Xt row padding: row j>>2, pad halfs [128..135] hold 4 floats
__device__ __forceinline__ float& vslot(_Float16* xt, int j) {
    return ((float*)(xt + (size_t)(j >> 2) * XT_S + 128))[j & 3];
}

// ---- pre-pass: Gth[e][d] = sum_n w1[n][d]*w2[n][e] (f16), plus
// g1f[d] = sum_n w1[n][d]*b2[n], g2f[d] = sum_n w2[n][d]*b1[n], cf = b1.b2 ----
__global__ __launch_bounds__(256) void pack_g(
    const float* __restrict__ w1, const float* __restrict__ w2,
    const float* __restrict__ b1, const float* __restrict__ b2,
    _Float16* __restrict__ gth, float* __restrict__ g1f,
    float* __restrict__ g2f, float* __restrict__ cf)
{
    const int t = threadIdx.x;
    if (blockIdx.x == 16) {
        if (t < 64) {
            float a = 0.f;
            #pragma unroll 8
            for (int n = 0; n < 64; ++n) a = fmaf(w1[n * 64 + t], b2[n], a);
            g1f[t] = a;
        } else if (t < 128) {
            const int d = t - 64;
            float a = 0.f;
            #pragma unroll 8
            for (int n = 0; n < 64; ++n) a = fmaf(w2[n * 64 + d], b1[n], a);
            g2f[d] = a;
        } else if (t == 128) {
            float a = 0.f;
            for (int n = 0; n < 64; ++n) a = fmaf(b1[n], b2[n], a);
            cf[0] = a;
        }
        return;
    }
    const int gid = blockIdx.x * 256 + t;
    const int d = gid & 63, e = gid >> 6;
    float a = 0.f;
    #pragma unroll 8
    for (int n = 0; n < 64; ++n) a = fmaf(w1[n * 64 + d], w2[n * 64 + e], a);
    gth[e * 64 + d] = (_Float16)a;
}

__global__ __launch_bounds__(256, 3) void space_graph_mfma5(
    const float* __restrict__ x, const _Float16* __restrict__ gth,
    const float* __restrict__ g1f, const float* __restrict__ g2f,
    const float* __restrict__ cf, float* __restrict__ out)
{
    // 64*136 + 128*72 + 128*72 = 27136 halfs = 54272 B -> 3 blocks/CU
    __shared__ _Float16 lds[64 * XT_S + NV * XH_S + NV * TA_S];
    _Float16* Xt = lds;                  // X^T: [dim][var] (+v in row pads)
    _Float16* Xh = lds + 64 * XT_S;      // X:   [var][dim] f16 (phase 3 B-op)
    _Float16* TA = Xh + NV * XH_S;       // T (phases 2-3), A_half (phases 4-5)

    const int t    = threadIdx.x;
    const int lane = t & 63;
    const int w    = t >> 6;             // wave -> owns S/O rows 32w..32w+31
    const int col  = lane & 15;
    const int quad = lane >> 4;

    const int blk = blockIdx.x;
    const int p = blk & (P - 1);
    const int h = (blk >> 6) & (H - 1);
    const int b = blk >> 9;
    const size_t base = ((size_t)b * L + (size_t)p) * D + (size_t)h * HEAD;

    // ---- Phase 1: build Xt (transposed) AND Xh (row-major) in f16 ----
    {
        const int c  = t & 15;           // float4 column
        const int tt = t >> 4;
        #pragma unroll
        for (int it = 0; it < 4; ++it) {
            const int j0 = 2 * (tt + 16 * it);
            const float4 v0 = *(const float4*)(x + base + (size_t)j0 * RS + c * 4);
            const float4 v1 = *(const float4*)(x + base + (size_t)(j0 + 1) * RS + c * 4);
            const float va[4] = {v0.x, v0.y, v0.z, v0.w};
            const float vb[4] = {v1.x, v1.y, v1.z, v1.w};
            half4h ra, rb;
            #pragma unroll
            for (int q = 0; q < 4; ++q) {
                const _Float16 ha = (_Float16)va[q];
                const _Float16 hb = (_Float16)vb[q];
                ra[q] = ha; rb[q] = hb;
                half2v pr; pr[0] = ha; pr[1] = hb;
                *(half2v*)&Xt[(4 * c + q) * XT_S + j0] = pr;
            }
            *(half4h*)&Xh[(size_t)j0 * XH_S + 4 * c] = ra;
            *(half4h*)&Xh[(size_t)(j0 + 1) * XH_S + 4 * c] = rb;
        }
    }

    // ---- Phase 2: T = X*G (MFMA); u,v rank-1 terms (VALU, f32) ----
    floatx4 tacc[2][4];
    #pragma unroll
    for (int mt = 0; mt < 2; ++mt)
        #pragma unroll
        for (int nt = 0; nt < 4; ++nt) tacc[mt][nt] = (floatx4)0.0f;

    half8 axf[2][2];
    float up[2] = {0.f, 0.f}, vp[2] = {0.f, 0.f};
    #pragma unroll
    for (int ks = 0; ks < 2; ++ks) {
        const float4 ga = *(const float4*)(g1f + quad * 8 + 32 * ks);
        const float4 gb = *(const float4*)(g1f + quad * 8 + 32 * ks + 4);
        const float4 ha = *(const float4*)(g2f + quad * 8 + 32 * ks);
        const float4 hb = *(const float4*)(g2f + quad * 8 + 32 * ks + 4);
        #pragma unroll
        for (int mt = 0; mt < 2; ++mt) {
            const int row = 32 * w + 16 * mt + col;
            const float* src = x + base + (size_t)row * RS + quad * 8 + 32 * ks;
            const float4 v0 = *(const float4*)src;
            const float4 v1 = *(const float4*)(src + 4);
            axf[mt][ks] = cvt8(v0, v1);
            up[mt] += v0.x * ga.x + v0.y * ga.y + v0.z * ga.z + v0.w * ga.w
                    + v1.x * gb.x + v1.y * gb.y + v1.z * gb.z + v1.w * gb.w;
            vp[mt] += v0.x * ha.x + v0.y * ha.y + v0.z * ha.z + v0.w * ha.w
                    + v1.x * hb.x + v1.y * hb.y + v1.z * hb.z + v1.w * hb.w;
        }
    }

    #pragma unroll
    for (int ks = 0; ks < 2; ++ks)
        #pragma unroll
        for (int nt = 0; nt < 4; ++nt) {
            const half8 gb8 = *(const half8*)&gth[(col + 16 * nt) * HEAD + quad * 8 + 32 * ks];
            #pragma unroll
            for (int mt = 0; mt < 2; ++mt)
                tacc[mt][nt] = mfma16(axf[mt][ks], gb8, tacc[mt][nt]);
        }

    // u stays in registers (quad-reduce; consumed by this wave via shfl).
    // v -> Xt row-padding LDS (cross-wave).
    float ureg[2];
    #pragma unroll
    for (int mt = 0; mt < 2; ++mt) {
        float uu = up[mt]; uu += __shfl_xor(uu, 16); uu += __shfl_xor(uu, 32);
        float vv = vp[mt]; vv += __shfl_xor(vv, 16); vv += __shfl_xor(vv, 32);
        ureg[mt] = uu;
        if (quad == 0) vslot(Xt, 32 * w + 16 * mt + col) = vv;
    }

    // T store (no bias -- biases live in u/v/c)
    #pragma unroll
    for (int mt = 0; mt < 2; ++mt)
        #pragma unroll
        for (int r = 0; r < 4; ++r) {
            const int R = 32 * w + 16 * mt + quad * 4 + r;
            _Float16* trow = &TA[R * TA_S + col];
            #pragma unroll
            for (int nt = 0; nt < 4; ++nt)
                trow[nt * 16] = (_Float16)(tacc[mt][nt][r]);
        }
    __syncthreads();   // the ONLY barrier: covers Xt/Xh (ph3/5) and v (ph3)

    // ---- Phase 3: S = T*X^T + (u_i + v_j + c) via accumulator init ----
    const float cc = cf[0];
    float ucr[2][4];
    #pragma unroll
    for (int mt = 0; mt < 2; ++mt)
        #pragma unroll
        for (int r = 0; r < 4; ++r)
            ucr[mt][r] = __shfl(ureg[mt], quad * 4 + r) + cc;
    float vrow[8];
    #pragma unroll
    for (int nt = 0; nt < 8; ++nt) vrow[nt] = vslot(Xt, col + 16 * nt);

    floatx4 sacc[2][8];
    #pragma unroll
    for (int mt = 0; mt < 2; ++mt)
        #pragma unroll
        for (int nt = 0; nt < 8; ++nt)
            #pragma unroll
            for (int r = 0; r < 4; ++r)
                sacc[mt][nt][r] = ucr[mt][r] + vrow[nt];

    #pragma unroll
    for (int ks = 0; ks < 2; ++ks) {
        half8 taf[2];
        #pragma unroll
        for (int mt = 0; mt < 2; ++mt)
            taf[mt] = *(const half8*)&TA[(32 * w + 16 * mt + col) * TA_S + quad * 8 + 32 * ks];
        #pragma unroll
        for (int nt = 0; nt < 8; ++nt) {
            const half8 xb = *(const half8*)&Xh[(col + 16 * nt) * XH_S + quad * 8 + 32 * ks];
            #pragma unroll
            for (int mt = 0; mt < 2; ++mt)
                sacc[mt][nt] = mfma16(taf[mt], xb, sacc[mt][nt]);
        }
    }

    // ---- Phase 4: A = softmax(gelu(S)); normalized weights back into sacc ----
    #pragma unroll
    for (int mt = 0; mt < 2; ++mt)
        #pragma unroll
        for (int r = 0; r < 4; ++r) {
            float wv[8]; float rs = 0.f;
            #pragma unroll
            for (int nt = 0; nt < 8; ++nt) {
                const float s  = sacc[mt][nt][r];
                const float u  = s * fmaf(s * s, 0.035677408137f, 0.7978845608f);
                const float em = __expf(-2.0f * u);
                const float g  = s * __builtin_amdgcn_rcpf(1.0f + em);
                const float e  = __expf(g);
                wv[nt] = e; rs += e;
            }
            rs += __shfl_xor(rs, 1); rs += __shfl_xor(rs, 2);
            rs += __shfl_xor(rs, 4); rs += __shfl_xor(rs, 8);
            const float inv = __builtin_amdgcn_rcpf(rs);
            #pragma unroll
            for (int nt = 0; nt < 8; ++nt) sacc[mt][nt][r] = wv[nt] * inv;
        }

    // ---- Phase 4a/5a: A_half <- vars 0..63 (wave-private rows), O += A*X ----
    #pragma unroll
    for (int mt = 0; mt < 2; ++mt)
        #pragma unroll
        for (int r = 0; r < 4; ++r) {
            const int R = 32 * w + 16 * mt + quad * 4 + r;
            _Float16* arow = &TA[R * TA_S + col];
            #pragma unroll
            for (int nt = 0; nt < 4; ++nt)
                arow[nt * 16] = (_Float16)(sacc[mt][nt][r]);
        }

    floatx4 oacc[2][4];
    #pragma unroll
    for (int mt = 0; mt < 2; ++mt)
        #pragma unroll
        for (int nt = 0; nt < 4; ++nt) oacc[mt][nt] = (floatx4)0.0f;

    #pragma unroll
    for (int kh = 0; kh < 2; ++kh) {
        half8 aaf[2];
        #pragma unroll
        for (int mt = 0; mt < 2; ++mt)
            aaf[mt] = *(const half8*)&TA[(32 * w + 16 * mt + col) * TA_S + quad * 8 + 32 * kh];
        #pragma unroll
        for (int nt = 0; nt < 4; ++nt) {
            const half8 xb = *(const half8*)&Xt[(col + 16 * nt) * XT_S + quad * 8 + 32 * kh];
            #pragma unroll
            for (int mt = 0; mt < 2; ++mt)
                oacc[mt][nt] = mfma16(aaf[mt], xb, oacc[mt][nt]);
        }
    }

    // ---- Phase 4b/5b: A_half <- vars 64..127, O += A*X ----
    #pragma unroll
    for (int mt = 0; mt < 2; ++mt)
        #pragma unroll
        for (int r = 0; r < 4; ++r) {
            const int R = 32 * w + 16 * mt + quad * 4 + r;
            _Float16* arow = &TA[R * TA_S + col];
            #pragma unroll
            for (int nt = 4; nt < 8; ++nt)
                arow[(nt - 4) * 16] = (_Float16)(sacc[mt][nt][r]);
        }

    #pragma unroll
    for (int kh = 0; kh < 2; ++kh) {
        half8 aaf[2];
        #pragma unroll
        for (int mt = 0; mt < 2; ++mt)
            aaf[mt] = *(const half8*)&TA[(32 * w + 16 * mt + col) * TA_S + quad * 8 + 32 * kh];
        #pragma unroll
        for (int nt = 0; nt < 4; ++nt) {
            const half8 xb = *(const half8*)&Xt[(col + 16 * nt) * XT_S + quad * 8 + 32 * (kh + 2)];
            #pragma unroll
            for (int mt = 0; mt < 2; ++mt)
                oacc[mt][nt] = mfma16(aaf[mt], xb, oacc[mt][nt]);
        }
    }

    // ---- Epilogue: direct stores (quad-wise 64B segments) ----
    #pragma unroll
    for (int mt = 0; mt < 2; ++mt)
        #pragma unroll
        for (int r = 0; r < 4; ++r) {
            const int i = 32 * w + 16 * mt + quad * 4 + r;
            float* orow = out + base + (size_t)i * RS + col;
            #pragma unroll
            for (int nt = 0; nt < 4; ++nt)
                orow[nt * 16] = oacc[mt][nt][r];
        }
}
} // namespace

extern "C" void kernel_launch(void* const* d_in, const int* in_sizes, int n_in,
                              void* d_out, int out_size, void* d_ws, size_t ws_size,
                              hipStream_t stream) {
    const float* x  = (const float*)d_in[0];
    const float* w1 = (const float*)d_in[1];
    const float* b1 = (const float*)d_in[2];
    const float* w2 = (const float*)d_in[3];
    const float* b2 = (const float*)d_in[4];
    float* out = (float*)d_out;

    _Float16* gth = (_Float16*)d_ws;                  // 8192 B: G^T f16 (64x64)
    float* g1f = (float*)((char*)d_ws + 8192);        // 256 B
    float* g2f = g1f + 64;                            // 256 B
    float* cf  = g2f + 64;                            // 4 B

    hipLaunchKernelGGL(pack_g, dim3(17), dim3(256), 0, stream,
                       w1, w2, b1, b2, gth, g1f, g2f, cf);
    hipLaunchKernelGGL(space_graph_mfma5, dim3(B * H * P), dim3(256), 0, stream,
                       x, gth, g1f, g2f, cf, out);
}